// Round 12
// baseline (410.914 us; speedup 1.0000x reference)
//
#include <hip/hip_runtime.h>

// SelfAttn (SAGAN block): B=4, C=512, N=4096, C8=64
// out = gamma * (V @ softmax(Q K^T)^T) + x ; also outputs attention [B,N,N].
// R12: k_fused split by c-half -> 512 blocks, 2 independent blocks/CU,
// 4 waves/SIMD (occupancy A/B vs R11; all else held fixed).

#define BB 4
#define CC 512
#define NN 4096
#define C8V 64

typedef __bf16 bf16x8 __attribute__((ext_vector_type(8)));
typedef float f32x4 __attribute__((ext_vector_type(4)));
typedef float f32x4v __attribute__((ext_vector_type(4)));
typedef unsigned short u16x8 __attribute__((ext_vector_type(8)));

#if __has_builtin(__builtin_amdgcn_exp2f)
#define EXP2(x) __builtin_amdgcn_exp2f(x)
#else
#define EXP2(x) exp2f(x)
#endif

#define MFMA16(a, b, c) __builtin_amdgcn_mfma_f32_16x16x32_bf16((a), (b), (c), 0, 0, 0)

__device__ __forceinline__ unsigned short f2b(float f) {
  union { float f; unsigned u; } x; x.f = f;
  unsigned u = x.u;
  u += 0x7fffu + ((u >> 16) & 1u);   // RNE round to bf16
  return (unsigned short)(u >> 16);
}

__device__ __forceinline__ float b2f(unsigned short s) {
  union { unsigned u; float f; } x; x.u = ((unsigned)s) << 16;
  return x.f;
}

__device__ __forceinline__ bf16x8 ldb8(const unsigned short* p) {
  return *reinterpret_cast<const bf16x8*>(p);
}

// ---------------- weights fp32 -> bf16 ----------------
__global__ __launch_bounds__(256) void k_cvt_w(
    const float* __restrict__ wq, const float* __restrict__ wk, const float* __restrict__ wv,
    unsigned short* __restrict__ wqb, unsigned short* __restrict__ wkb, unsigned short* __restrict__ wvb) {
  int i = blockIdx.x * 256 + threadIdx.x;
  if (i < 32768)        wqb[i] = f2b(wq[i]);
  else if (i < 65536)   wkb[i - 32768] = f2b(wk[i - 32768]);
  else if (i < 327680)  wvb[i - 65536] = f2b(wv[i - 65536]);
}

// ---------------- transpose [C][N] f32 -> [N][C] bf16 (per batch) ----------------
__global__ __launch_bounds__(256) void k_transpose(const float* __restrict__ src,
                                                   unsigned short* __restrict__ dst) {
  __shared__ float tile[64][65];
  int b = blockIdx.z, c0 = blockIdx.y * 64, n0 = blockIdx.x * 64;
  const float* s = src + (size_t)b * CC * NN;
  unsigned short* d = dst + (size_t)b * NN * CC;
  int t = threadIdx.x;
#pragma unroll
  for (int j = 0; j < 4; j++) {
    int idx = t + j * 256, row = idx >> 4, col4 = (idx & 15) * 4;
    f32x4v v4 = *reinterpret_cast<const f32x4v*>(&s[(size_t)(c0 + row) * NN + n0 + col4]);
    tile[row][col4 + 0] = v4.x; tile[row][col4 + 1] = v4.y;
    tile[row][col4 + 2] = v4.z; tile[row][col4 + 3] = v4.w;
  }
  __syncthreads();
#pragma unroll
  for (int j = 0; j < 4; j++) {
    int idx = t + j * 256, nrow = idx >> 4, c4 = (idx & 15) * 4;
    ushort4 o;
    o.x = f2b(tile[c4 + 0][nrow]); o.y = f2b(tile[c4 + 1][nrow]);
    o.z = f2b(tile[c4 + 2][nrow]); o.w = f2b(tile[c4 + 3][nrow]);
    *reinterpret_cast<ushort4*>(&d[(size_t)(n0 + nrow) * CC + c0 + c4]) = o;
  }
}

// ---------------- Q/K projection ----------------
__global__ __launch_bounds__(256) void k_proj64(const unsigned short* __restrict__ aT,
                                                const unsigned short* __restrict__ wb,
                                                const float* __restrict__ bias,
                                                unsigned short* __restrict__ out, float scale) {
  int wave = threadIdx.x >> 6, l = threadIdx.x & 63;
  int r0 = blockIdx.x * 64 + wave * 16;
  int lr = l & 15, lk = l >> 4;
  const unsigned short* arow = aT + (size_t)(r0 + lr) * CC + lk * 8;
  f32x4 acc[4] = {};
  for (int ks = 0; ks < 16; ks++) {
    bf16x8 a = ldb8(arow + ks * 32);
#pragma unroll
    for (int cg = 0; cg < 4; cg++) {
      bf16x8 bfr = ldb8(wb + (size_t)(cg * 16 + lr) * CC + ks * 32 + lk * 8);
      acc[cg] = MFMA16(a, bfr, acc[cg]);
    }
  }
#pragma unroll
  for (int cg = 0; cg < 4; cg++) {
    int o = cg * 16 + lr;
    float bv = bias[o];
#pragma unroll
    for (int i = 0; i < 4; i++) {
      int row = r0 + lk * 4 + i;
      out[(size_t)row * C8V + o] = f2b((acc[cg][i] + bv) * scale);
    }
  }
}

// ---------------- V projection ----------------
__global__ __launch_bounds__(256) void k_projv(const unsigned short* __restrict__ wvb,
                                               const unsigned short* __restrict__ xT,
                                               const float* __restrict__ bv,
                                               unsigned short* __restrict__ v) {
  int b = blockIdx.z, c0 = blockIdx.y * 64;
  int wave = threadIdx.x >> 6, l = threadIdx.x & 63;
  int n0 = blockIdx.x * 256 + wave * 64;
  int lr = l & 15, lk = l >> 4;
  const unsigned short* xb = xT + (size_t)b * NN * CC;
  f32x4 acc[4][4] = {};
  for (int ks = 0; ks < 16; ks++) {
    bf16x8 a[4], bfr[4];
#pragma unroll
    for (int rg = 0; rg < 4; rg++)
      a[rg] = ldb8(wvb + (size_t)(c0 + rg * 16 + lr) * CC + ks * 32 + lk * 8);
#pragma unroll
    for (int cg = 0; cg < 4; cg++)
      bfr[cg] = ldb8(xb + (size_t)(n0 + cg * 16 + lr) * CC + ks * 32 + lk * 8);
#pragma unroll
    for (int rg = 0; rg < 4; rg++)
#pragma unroll
      for (int cg = 0; cg < 4; cg++)
        acc[rg][cg] = MFMA16(a[rg], bfr[cg], acc[rg][cg]);
  }
  unsigned short* vb = v + (size_t)b * CC * NN;
#pragma unroll
  for (int rg = 0; rg < 4; rg++)
#pragma unroll
    for (int i = 0; i < 4; i++) {
      int row = c0 + rg * 16 + lk * 4 + i;
      float bias = bv[row];
#pragma unroll
      for (int cg = 0; cg < 4; cg++) {
        int col = n0 + cg * 16 + lr;
        vb[(size_t)row * NN + col] = f2b(acc[rg][cg][i] + bias);
      }
    }
}

// ---------------- softmax inverse-denominator: inv[b*N + row] ----------------
__global__ __launch_bounds__(512) void k_sminv(const unsigned short* __restrict__ q,
                                               const unsigned short* __restrict__ kt,
                                               float* __restrict__ invp) {
  __shared__ float psum[8][16];
  int b = blockIdx.y;
  int w = threadIdx.x >> 6, l = threadIdx.x & 63;
  int rg = w >> 2, cq = w & 3;
  int r0 = blockIdx.x * 32 + rg * 16;
  int lr = l & 15, lk = l >> 4;
  const unsigned short* qp = q + (size_t)(b * NN + r0 + lr) * C8V + lk * 8;
  bf16x8 aq0 = ldb8(qp);
  bf16x8 aq1 = ldb8(qp + 32);
  const unsigned short* ktb = kt + (size_t)b * NN * C8V;
  int jt0 = cq * 16;

  float lsum[4] = {0.f, 0.f, 0.f, 0.f};
  for (int jt = jt0; jt < jt0 + 16; jt++) {
    f32x4 acc[4] = {};
#pragma unroll
    for (int cg = 0; cg < 4; cg++) {
      const unsigned short* kp = ktb + (size_t)(jt * 64 + cg * 16 + lr) * C8V + lk * 8;
      acc[cg] = MFMA16(aq0, ldb8(kp), acc[cg]);
      acc[cg] = MFMA16(aq1, ldb8(kp + 32), acc[cg]);
    }
#pragma unroll
    for (int i = 0; i < 4; i++)
      lsum[i] += (EXP2(acc[0][i]) + EXP2(acc[1][i])) + (EXP2(acc[2][i]) + EXP2(acc[3][i]));
  }
#pragma unroll
  for (int i = 0; i < 4; i++) {
#pragma unroll
    for (int mm = 1; mm < 16; mm <<= 1) lsum[i] += __shfl_xor(lsum[i], mm);
  }
  if (lr == 0) {
#pragma unroll
    for (int i = 0; i < 4; i++) psum[w][lk * 4 + i] = lsum[i];
  }
  __syncthreads();
  if (cq == 0 && lr == 0) {
#pragma unroll
    for (int i = 0; i < 4; i++) {
      int rr = lk * 4 + i;
      float s = psum[rg * 4 + 0][rr] + psum[rg * 4 + 1][rr] +
                psum[rg * 4 + 2][rr] + psum[rg * 4 + 3][rr];
      invp[(size_t)b * NN + r0 + rr] = 1.0f / s;
    }
  }
}

// ---------------- fused: energy recompute + att write + PV + epilogue ----------------
// 512 blocks (2/CU, 4 waves/SIMD): block = (batch, m-tile of 64, c-HALF).
// Both c-half blocks build the full P tile (QK^T duplicated, cheap); only
// chalf==0 writes att. PV per wave covers 32 c-rows (acc 32 VGPR).
// Period = 2 chunks, lgkm-only barriers, load-before-store order (R11 form).
__global__ __launch_bounds__(512, 4) void k_fused(const unsigned short* __restrict__ q,
                                                  const unsigned short* __restrict__ kt,
                                                  const unsigned short* __restrict__ v,
                                                  const float* __restrict__ invp,
                                                  const float* __restrict__ x,
                                                  const float* __restrict__ gamma,
                                                  float* __restrict__ out,
                                                  float* __restrict__ att) {
  __shared__ unsigned short smP[2][2 * 64 * 64];   // 2 x 16 KiB (2 chunks/period)

  int bid = blockIdx.x;
  int b = (bid & 7) >> 1;                        // XCD id = bid % 8
  int idx = (bid >> 3) * 2 + (bid & 1);          // 0..127 within batch
  int m0 = (idx >> 1) * 64;                      // 64 m-tiles per batch
  int chalf = idx & 1;                           // c-half: 0 -> c 0..255, 1 -> 256..511
  int t = threadIdx.x, w = t >> 6, l = t & 63, lr = l & 15, lk = l >> 4;
  int rg = w >> 1, nh = w & 1;                   // QK^T: rows rg*16.., col-half nh
  int c0w = chalf * 256 + w * 32;                // PV: 32 c-rows per wave
  int mrow = t >> 3, col8 = t & 7;               // ATTST: row, col-octet

  const unsigned short* ktb = kt + (size_t)b * NN * C8V;
  const unsigned short* vb = v + (size_t)b * CC * NN;
  float* ab = att + (size_t)b * NN * NN;

  const unsigned short* qp = q + (size_t)(b * NN + m0 + rg * 16 + lr) * C8V + lk * 8;
  bf16x8 aq0 = ldb8(qp), aq1 = ldb8(qp + 32);
  f32x4v invv = *reinterpret_cast<const f32x4v*>(&invp[(size_t)b * NN + m0 + rg * 16 + lk * 4]);

#define QKSM(BUF, U, JT)                                                       \
  {                                                                            \
    bf16x8 k0[2], k1[2];                                                       \
    _Pragma("unroll")                                                          \
    for (int cg = 0; cg < 2; cg++) {                                           \
      const unsigned short* kp =                                               \
          ktb + (size_t)((JT) * 64 + nh * 32 + cg * 16 + lr) * C8V + lk * 8;   \
      k0[cg] = ldb8(kp);                                                       \
      k1[cg] = ldb8(kp + 32);                                                  \
    }                                                                          \
    char* pbuf = reinterpret_cast<char*>(&smP[BUF][0]) + (U) * 8192;           \
    _Pragma("unroll")                                                          \
    for (int cg = 0; cg < 2; cg++) {                                           \
      f32x4 z = {};                                                            \
      z = MFMA16(aq0, k0[cg], z);                                              \
      z = MFMA16(aq1, k1[cg], z);                                              \
      int nl = nh * 32 + cg * 16 + lr;                                         \
      _Pragma("unroll")                                                        \
      for (int i = 0; i < 4; i++) {                                            \
        int ml = rg * 16 + lk * 4 + i;                                         \
        float p = EXP2(z[i]) * invv[i];                                        \
        *reinterpret_cast<unsigned short*>(                                    \
            pbuf + ml * 128 + ((nl * 2) ^ ((ml & 7) << 4))) = f2b(p);          \
      }                                                                        \
    }                                                                          \
  }

#define LDV(DST, JT)                                                           \
  _Pragma("unroll")                                                            \
  for (int rg2 = 0; rg2 < 2; rg2++) {                                          \
    const unsigned short* vp =                                                 \
        vb + (size_t)(c0w + rg2 * 16 + lr) * NN + (JT) * 64 + lk * 8;          \
    DST[rg2 * 2] = ldb8(vp);                                                   \
    DST[rg2 * 2 + 1] = ldb8(vp + 32);                                          \
  }

#define ATTST(BUF, U, JT)                                                      \
  if (chalf == 0) {                                                            \
    const char* pr = reinterpret_cast<const char*>(&smP[BUF][0]) + (U) * 8192; \
    u16x8 raw = *reinterpret_cast<const u16x8*>(                               \
        pr + mrow * 128 + ((col8 * 16) ^ ((mrow & 7) << 4)));                  \
    f32x4v lo, hi;                                                             \
    lo.x = b2f(raw[0]); lo.y = b2f(raw[1]); lo.z = b2f(raw[2]);                \
    lo.w = b2f(raw[3]); hi.x = b2f(raw[4]); hi.y = b2f(raw[5]);                \
    hi.z = b2f(raw[6]); hi.w = b2f(raw[7]);                                    \
    float* dst = &ab[(size_t)(m0 + mrow) * NN + (JT) * 64 + col8 * 8];         \
    __builtin_nontemporal_store(lo, reinterpret_cast<f32x4v*>(dst));           \
    __builtin_nontemporal_store(hi, reinterpret_cast<f32x4v*>(dst + 4));       \
  }

#define PVU(BUF, U, VR)                                                        \
  {                                                                            \
    const char* pr = reinterpret_cast<const char*>(&smP[BUF][0]) + (U) * 8192; \
    _Pragma("unroll")                                                          \
    for (int ks = 0; ks < 2; ks++) {                                           \
      bf16x8 bfr[4];                                                           \
      _Pragma("unroll")                                                        \
      for (int cg = 0; cg < 4; cg++) {                                         \
        int mr = cg * 16 + lr;                                                 \
        bfr[cg] = *reinterpret_cast<const bf16x8*>(                            \
            pr + mr * 128 + ((ks * 64 + lk * 16) ^ ((mr & 7) << 4)));          \
      }                                                                        \
      _Pragma("unroll")                                                        \
      for (int rg2 = 0; rg2 < 2; rg2++)                                        \
        _Pragma("unroll")                                                      \
        for (int cg = 0; cg < 4; cg++)                                         \
          acc[rg2][cg] = MFMA16(VR[rg2 * 2 + ks], bfr[cg], acc[rg2][cg]);      \
    }                                                                          \
  }

#define SYNC_NODRAIN()                                   \
  asm volatile("s_waitcnt lgkmcnt(0)" ::: "memory");     \
  __builtin_amdgcn_s_barrier();                          \
  __builtin_amdgcn_sched_barrier(0);

  f32x4 acc[2][4] = {};
  bf16x8 vr0[4], vr1[4];

  // prologue: chunks 0,1 -> buf 0
  QKSM(0, 0, 0);
  QKSM(0, 1, 1);
  SYNC_NODRAIN();

  for (int g = 0; g < 32; g++) {
    int cur = g & 1;
    if (g < 31) {
      QKSM(cur ^ 1, 0, (g + 1) * 2);
      QKSM(cur ^ 1, 1, (g + 1) * 2 + 1);
    }
    LDV(vr0, g * 2);
    LDV(vr1, g * 2 + 1);
    ATTST(cur, 0, g * 2);
    ATTST(cur, 1, g * 2 + 1);
    PVU(cur, 0, vr0);
    PVU(cur, 1, vr1);
    SYNC_NODRAIN();
  }
#undef QKSM
#undef LDV
#undef ATTST
#undef PVU
#undef SYNC_NODRAIN

  // ---- epilogue: out = gamma*acc + x (this block's c-half only) ----
  float gm = gamma[0];
  const float* xb = x + (size_t)b * CC * NN;
  float* ob = out + (size_t)b * CC * NN;
#pragma unroll
  for (int rg2 = 0; rg2 < 2; rg2++)
#pragma unroll
    for (int i = 0; i < 4; i++) {
      int row = c0w + rg2 * 16 + lk * 4 + i;
#pragma unroll
      for (int cg = 0; cg < 4; cg++) {
        int col = m0 + cg * 16 + lr;
        size_t off = (size_t)row * NN + col;
        float xv = __builtin_nontemporal_load(&xb[off]);
        __builtin_nontemporal_store(gm * acc[rg2][cg][i] + xv, &ob[off]);
      }
    }
}

extern "C" void kernel_launch(void* const* d_in, const int* in_sizes, int n_in,
                              void* d_out, int out_size, void* d_ws, size_t ws_size,
                              hipStream_t stream) {
  const float* x  = (const float*)d_in[0];
  const float* y  = (const float*)d_in[1];
  const float* wq = (const float*)d_in[2];
  const float* bq = (const float*)d_in[3];
  const float* wk = (const float*)d_in[4];
  const float* bk = (const float*)d_in[5];
  const float* wv = (const float*)d_in[6];
  const float* bv = (const float*)d_in[7];
  const float* gamma = (const float*)d_in[8];

  float* out = (float*)d_out;
  float* att = out + (size_t)BB * CC * NN;   // attention region of d_out

  // workspace layout (bytes)
  char* ws = (char*)d_ws;
  unsigned short* yT  = (unsigned short*)(ws);                 // 16 MiB  [B][N][C] bf16
  unsigned short* xT  = (unsigned short*)(ws + 16777216);      // 16 MiB
  unsigned short* q   = (unsigned short*)(ws + 33554432);      // 2 MiB   [B*N][64]
  unsigned short* kt  = (unsigned short*)(ws + 35651584);      // 2 MiB   [B*N][64]
  unsigned short* v   = (unsigned short*)(ws + 37748736);      // 16 MiB  [B][C][N]
  unsigned short* wqb = (unsigned short*)(ws + 54525952);      // 64 KiB
  unsigned short* wkb = (unsigned short*)(ws + 54591488);      // 64 KiB
  unsigned short* wvb = (unsigned short*)(ws + 54657024);      // 512 KiB
  float*          inv = (float*)(ws + 55181312);               // 64 KiB  [B*N]
  if (ws_size < 55246848u) return;  // insufficient scratch -> fail loudly

  k_cvt_w<<<1280, 256, 0, stream>>>(wq, wk, wv, wqb, wkb, wvb);
  k_transpose<<<dim3(64, 8, 4), 256, 0, stream>>>(y, yT);
  k_transpose<<<dim3(64, 8, 4), 256, 0, stream>>>(x, xT);
  k_proj64<<<256, 256, 0, stream>>>(yT, wqb, bq, q, 1.44269504088896f);  // q pre-scaled by log2(e)
  k_proj64<<<256, 256, 0, stream>>>(yT, wkb, bk, kt, 1.0f);
  k_projv<<<dim3(16, 8, 4), 256, 0, stream>>>(wvb, xT, bv, v);
  k_sminv<<<dim3(128, 4), 512, 0, stream>>>(q, kt, inv);
  k_fused<<<512, 512, 0, stream>>>(q, kt, v, inv, x, gamma, out, att);
}

// Round 13
// 345.606 us; speedup vs baseline: 1.1890x; 1.1890x over previous
//
#include <hip/hip_runtime.h>

// SelfAttn (SAGAN block): B=4, C=512, N=4096, C8=64
// out = gamma * (V @ softmax(Q K^T)^T) + x ; also outputs attention [B,N,N].
// R13: FIFO-clean pipeline in k_fused. vmcnt retires IN ORDER, so any load
// issued after a store waits for the store's HBM ack when consumed. Rule:
// per period issue [loads][stores][compute], and consume only PREVIOUS-
// period loads (register double-buffer) -> store drain overlaps a full
// period instead of serializing per chunk.

#define BB 4
#define CC 512
#define NN 4096
#define C8V 64

typedef __bf16 bf16x8 __attribute__((ext_vector_type(8)));
typedef float f32x4 __attribute__((ext_vector_type(4)));
typedef float f32x4v __attribute__((ext_vector_type(4)));
typedef unsigned short u16x8 __attribute__((ext_vector_type(8)));

#if __has_builtin(__builtin_amdgcn_exp2f)
#define EXP2(x) __builtin_amdgcn_exp2f(x)
#else
#define EXP2(x) exp2f(x)
#endif

#define MFMA16(a, b, c) __builtin_amdgcn_mfma_f32_16x16x32_bf16((a), (b), (c), 0, 0, 0)

__device__ __forceinline__ unsigned short f2b(float f) {
  union { float f; unsigned u; } x; x.f = f;
  unsigned u = x.u;
  u += 0x7fffu + ((u >> 16) & 1u);   // RNE round to bf16
  return (unsigned short)(u >> 16);
}

__device__ __forceinline__ float b2f(unsigned short s) {
  union { unsigned u; float f; } x; x.u = ((unsigned)s) << 16;
  return x.f;
}

__device__ __forceinline__ bf16x8 ldb8(const unsigned short* p) {
  return *reinterpret_cast<const bf16x8*>(p);
}

// ---------------- weights fp32 -> bf16 ----------------
__global__ __launch_bounds__(256) void k_cvt_w(
    const float* __restrict__ wq, const float* __restrict__ wk, const float* __restrict__ wv,
    unsigned short* __restrict__ wqb, unsigned short* __restrict__ wkb, unsigned short* __restrict__ wvb) {
  int i = blockIdx.x * 256 + threadIdx.x;
  if (i < 32768)        wqb[i] = f2b(wq[i]);
  else if (i < 65536)   wkb[i - 32768] = f2b(wk[i - 32768]);
  else if (i < 327680)  wvb[i - 65536] = f2b(wv[i - 65536]);
}

// ---------------- transpose [C][N] f32 -> [N][C] bf16 (per batch) ----------------
__global__ __launch_bounds__(256) void k_transpose(const float* __restrict__ src,
                                                   unsigned short* __restrict__ dst) {
  __shared__ float tile[64][65];
  int b = blockIdx.z, c0 = blockIdx.y * 64, n0 = blockIdx.x * 64;
  const float* s = src + (size_t)b * CC * NN;
  unsigned short* d = dst + (size_t)b * NN * CC;
  int t = threadIdx.x;
#pragma unroll
  for (int j = 0; j < 4; j++) {
    int idx = t + j * 256, row = idx >> 4, col4 = (idx & 15) * 4;
    f32x4v v4 = *reinterpret_cast<const f32x4v*>(&s[(size_t)(c0 + row) * NN + n0 + col4]);
    tile[row][col4 + 0] = v4.x; tile[row][col4 + 1] = v4.y;
    tile[row][col4 + 2] = v4.z; tile[row][col4 + 3] = v4.w;
  }
  __syncthreads();
#pragma unroll
  for (int j = 0; j < 4; j++) {
    int idx = t + j * 256, nrow = idx >> 4, c4 = (idx & 15) * 4;
    ushort4 o;
    o.x = f2b(tile[c4 + 0][nrow]); o.y = f2b(tile[c4 + 1][nrow]);
    o.z = f2b(tile[c4 + 2][nrow]); o.w = f2b(tile[c4 + 3][nrow]);
    *reinterpret_cast<ushort4*>(&d[(size_t)(n0 + nrow) * CC + c0 + c4]) = o;
  }
}

// ---------------- Q/K projection ----------------
__global__ __launch_bounds__(256) void k_proj64(const unsigned short* __restrict__ aT,
                                                const unsigned short* __restrict__ wb,
                                                const float* __restrict__ bias,
                                                unsigned short* __restrict__ out, float scale) {
  int wave = threadIdx.x >> 6, l = threadIdx.x & 63;
  int r0 = blockIdx.x * 64 + wave * 16;
  int lr = l & 15, lk = l >> 4;
  const unsigned short* arow = aT + (size_t)(r0 + lr) * CC + lk * 8;
  f32x4 acc[4] = {};
  for (int ks = 0; ks < 16; ks++) {
    bf16x8 a = ldb8(arow + ks * 32);
#pragma unroll
    for (int cg = 0; cg < 4; cg++) {
      bf16x8 bfr = ldb8(wb + (size_t)(cg * 16 + lr) * CC + ks * 32 + lk * 8);
      acc[cg] = MFMA16(a, bfr, acc[cg]);
    }
  }
#pragma unroll
  for (int cg = 0; cg < 4; cg++) {
    int o = cg * 16 + lr;
    float bv = bias[o];
#pragma unroll
    for (int i = 0; i < 4; i++) {
      int row = r0 + lk * 4 + i;
      out[(size_t)row * C8V + o] = f2b((acc[cg][i] + bv) * scale);
    }
  }
}

// ---------------- V projection ----------------
__global__ __launch_bounds__(256) void k_projv(const unsigned short* __restrict__ wvb,
                                               const unsigned short* __restrict__ xT,
                                               const float* __restrict__ bv,
                                               unsigned short* __restrict__ v) {
  int b = blockIdx.z, c0 = blockIdx.y * 64;
  int wave = threadIdx.x >> 6, l = threadIdx.x & 63;
  int n0 = blockIdx.x * 256 + wave * 64;
  int lr = l & 15, lk = l >> 4;
  const unsigned short* xb = xT + (size_t)b * NN * CC;
  f32x4 acc[4][4] = {};
  for (int ks = 0; ks < 16; ks++) {
    bf16x8 a[4], bfr[4];
#pragma unroll
    for (int rg = 0; rg < 4; rg++)
      a[rg] = ldb8(wvb + (size_t)(c0 + rg * 16 + lr) * CC + ks * 32 + lk * 8);
#pragma unroll
    for (int cg = 0; cg < 4; cg++)
      bfr[cg] = ldb8(xb + (size_t)(n0 + cg * 16 + lr) * CC + ks * 32 + lk * 8);
#pragma unroll
    for (int rg = 0; rg < 4; rg++)
#pragma unroll
      for (int cg = 0; cg < 4; cg++)
        acc[rg][cg] = MFMA16(a[rg], bfr[cg], acc[rg][cg]);
  }
  unsigned short* vb = v + (size_t)b * CC * NN;
#pragma unroll
  for (int rg = 0; rg < 4; rg++)
#pragma unroll
    for (int i = 0; i < 4; i++) {
      int row = c0 + rg * 16 + lk * 4 + i;
      float bias = bv[row];
#pragma unroll
      for (int cg = 0; cg < 4; cg++) {
        int col = n0 + cg * 16 + lr;
        vb[(size_t)row * NN + col] = f2b(acc[rg][cg][i] + bias);
      }
    }
}

// ---------------- softmax inverse-denominator: inv[b*N + row] ----------------
__global__ __launch_bounds__(512) void k_sminv(const unsigned short* __restrict__ q,
                                               const unsigned short* __restrict__ kt,
                                               float* __restrict__ invp) {
  __shared__ float psum[8][16];
  int b = blockIdx.y;
  int w = threadIdx.x >> 6, l = threadIdx.x & 63;
  int rg = w >> 2, cq = w & 3;
  int r0 = blockIdx.x * 32 + rg * 16;
  int lr = l & 15, lk = l >> 4;
  const unsigned short* qp = q + (size_t)(b * NN + r0 + lr) * C8V + lk * 8;
  bf16x8 aq0 = ldb8(qp);
  bf16x8 aq1 = ldb8(qp + 32);
  const unsigned short* ktb = kt + (size_t)b * NN * C8V;
  int jt0 = cq * 16;

  float lsum[4] = {0.f, 0.f, 0.f, 0.f};
  for (int jt = jt0; jt < jt0 + 16; jt++) {
    f32x4 acc[4] = {};
#pragma unroll
    for (int cg = 0; cg < 4; cg++) {
      const unsigned short* kp = ktb + (size_t)(jt * 64 + cg * 16 + lr) * C8V + lk * 8;
      acc[cg] = MFMA16(aq0, ldb8(kp), acc[cg]);
      acc[cg] = MFMA16(aq1, ldb8(kp + 32), acc[cg]);
    }
#pragma unroll
    for (int i = 0; i < 4; i++)
      lsum[i] += (EXP2(acc[0][i]) + EXP2(acc[1][i])) + (EXP2(acc[2][i]) + EXP2(acc[3][i]));
  }
#pragma unroll
  for (int i = 0; i < 4; i++) {
#pragma unroll
    for (int mm = 1; mm < 16; mm <<= 1) lsum[i] += __shfl_xor(lsum[i], mm);
  }
  if (lr == 0) {
#pragma unroll
    for (int i = 0; i < 4; i++) psum[w][lk * 4 + i] = lsum[i];
  }
  __syncthreads();
  if (cq == 0 && lr == 0) {
#pragma unroll
    for (int i = 0; i < 4; i++) {
      int rr = lk * 4 + i;
      float s = psum[rg * 4 + 0][rr] + psum[rg * 4 + 1][rr] +
                psum[rg * 4 + 2][rr] + psum[rg * 4 + 3][rr];
      invp[(size_t)b * NN + r0 + rr] = 1.0f / s;
    }
  }
}

// ---------------- fused: energy recompute + att write + PV + epilogue ----------------
// Grid 256 (1 block/CU), XCD-pinned, R11 geometry (wave = 64 c-rows).
// Period g (one 64-col chunk), FIFO-clean:
//   [L] LDKT(g+2), LDV(g+1)        <- global loads FIRST (never behind stores)
//   [S] ATTST(g): LDS P readback -> 2x dwordx4 NT att store
//   [C] QKSM(g+1) from kt regs of period g-1 -> P(g+1) -> LDS buf^1
//       PV(g) from v regs of period g-1 + LDS P(g)    (setprio around MFMA)
//   lgkm-only barrier.
// All consumed global data is a full period old, so its in-order vmcnt wait
// only needs period-(g-1) ops (incl. store acks) retired -> store drain
// overlaps the whole period instead of stalling each chunk.
__global__ __launch_bounds__(512, 2) void k_fused(const unsigned short* __restrict__ q,
                                                  const unsigned short* __restrict__ kt,
                                                  const unsigned short* __restrict__ v,
                                                  const float* __restrict__ invp,
                                                  const float* __restrict__ x,
                                                  const float* __restrict__ gamma,
                                                  float* __restrict__ out,
                                                  float* __restrict__ att) {
  __shared__ unsigned short smP[2][64 * 64];   // 2 x 8 KiB P tiles

  int bid = blockIdx.x;
  int b = (bid & 7) >> 1;                       // XCD id = bid % 8
  int m0 = ((bid >> 3) * 2 + (bid & 1)) * 64;   // 64 m-tiles per batch
  int t = threadIdx.x, w = t >> 6, l = t & 63, lr = l & 15, lk = l >> 4;
  int rg = w >> 1, nh = w & 1;                  // QK^T: rows rg*16.., col-half nh
  int c0w = w * 64;                             // PV: 64 c-rows per wave
  int mrow = t >> 3, col8 = t & 7;              // ATTST: row, col-octet

  const unsigned short* ktb = kt + (size_t)b * NN * C8V;
  const unsigned short* vb = v + (size_t)b * CC * NN;
  float* ab = att + (size_t)b * NN * NN;

  const unsigned short* qp = q + (size_t)(b * NN + m0 + rg * 16 + lr) * C8V + lk * 8;
  bf16x8 aq0 = ldb8(qp), aq1 = ldb8(qp + 32);
  f32x4v invv = *reinterpret_cast<const f32x4v*>(&invp[(size_t)b * NN + m0 + rg * 16 + lk * 4]);

#define LDKT(D, JT)                                                            \
  _Pragma("unroll")                                                            \
  for (int cg = 0; cg < 2; cg++) {                                             \
    const unsigned short* kp =                                                 \
        ktb + (size_t)((JT) * 64 + nh * 32 + cg * 16 + lr) * C8V + lk * 8;     \
    D[cg * 2] = ldb8(kp);                                                      \
    D[cg * 2 + 1] = ldb8(kp + 32);                                             \
  }

#define LDV(D, JT)                                                             \
  _Pragma("unroll")                                                            \
  for (int rg2 = 0; rg2 < 4; rg2++) {                                          \
    const unsigned short* vp =                                                 \
        vb + (size_t)(c0w + rg2 * 16 + lr) * NN + (JT) * 64 + lk * 8;          \
    D[rg2 * 2] = ldb8(vp);                                                     \
    D[rg2 * 2 + 1] = ldb8(vp + 32);                                            \
  }

// QK^T from REGISTER kt set -> softmax -> bf16 P into LDS buf (no globals)
#define QKSM(KT, BUF)                                                          \
  {                                                                            \
    char* pbuf = reinterpret_cast<char*>(&smP[BUF][0]);                        \
    _Pragma("unroll")                                                          \
    for (int cg = 0; cg < 2; cg++) {                                           \
      f32x4 z = {};                                                            \
      z = MFMA16(aq0, KT[cg * 2], z);                                          \
      z = MFMA16(aq1, KT[cg * 2 + 1], z);                                      \
      int nl = nh * 32 + cg * 16 + lr;                                         \
      _Pragma("unroll")                                                        \
      for (int i = 0; i < 4; i++) {                                            \
        int ml = rg * 16 + lk * 4 + i;                                         \
        float p = EXP2(z[i]) * invv[i];                                        \
        *reinterpret_cast<unsigned short*>(                                    \
            pbuf + ml * 128 + ((nl * 2) ^ ((ml & 7) << 4))) = f2b(p);          \
      }                                                                        \
    }                                                                          \
  }

#define ATTST(BUF, JT)                                                         \
  {                                                                            \
    const char* pr = reinterpret_cast<const char*>(&smP[BUF][0]);              \
    u16x8 raw = *reinterpret_cast<const u16x8*>(                               \
        pr + mrow * 128 + ((col8 * 16) ^ ((mrow & 7) << 4)));                  \
    f32x4v lo, hi;                                                             \
    lo.x = b2f(raw[0]); lo.y = b2f(raw[1]); lo.z = b2f(raw[2]);                \
    lo.w = b2f(raw[3]); hi.x = b2f(raw[4]); hi.y = b2f(raw[5]);                \
    hi.z = b2f(raw[6]); hi.w = b2f(raw[7]);                                    \
    float* dst = &ab[(size_t)(m0 + mrow) * NN + (JT) * 64 + col8 * 8];         \
    __builtin_nontemporal_store(lo, reinterpret_cast<f32x4v*>(dst));           \
    __builtin_nontemporal_store(hi, reinterpret_cast<f32x4v*>(dst + 4));       \
  }

#define PV(VR, BUF)                                                            \
  {                                                                            \
    const char* pr = reinterpret_cast<const char*>(&smP[BUF][0]);              \
    __builtin_amdgcn_s_setprio(1);                                             \
    _Pragma("unroll")                                                          \
    for (int ks = 0; ks < 2; ks++) {                                           \
      bf16x8 bfr[4];                                                           \
      _Pragma("unroll")                                                        \
      for (int cg = 0; cg < 4; cg++) {                                         \
        int mr = cg * 16 + lr;                                                 \
        bfr[cg] = *reinterpret_cast<const bf16x8*>(                            \
            pr + mr * 128 + ((ks * 64 + lk * 16) ^ ((mr & 7) << 4)));          \
      }                                                                        \
      _Pragma("unroll")                                                        \
      for (int rg2 = 0; rg2 < 4; rg2++)                                        \
        _Pragma("unroll")                                                      \
        for (int cg = 0; cg < 4; cg++)                                         \
          acc[rg2][cg] = MFMA16(VR[rg2 * 2 + ks], bfr[cg], acc[rg2][cg]);      \
    }                                                                          \
    __builtin_amdgcn_s_setprio(0);                                             \
  }

#define SB() __builtin_amdgcn_sched_barrier(0);

#define SYNC_NODRAIN()                                   \
  asm volatile("s_waitcnt lgkmcnt(0)" ::: "memory");     \
  __builtin_amdgcn_s_barrier();                          \
  __builtin_amdgcn_sched_barrier(0);

  f32x4 acc[4][4] = {};
  bf16x8 ktA[4], ktB[4];   // kt sets: even chunks -> A, odd -> B
  bf16x8 vA[8], vB[8];     // v sets: even chunks -> A, odd -> B

  // prologue: kt(0)->A, v(0)->A, P(0)->buf0, kt(1)->B
  LDKT(ktA, 0);
  LDV(vA, 0);
  QKSM(ktA, 0);            // consumes ktA (no stores older -> clean wait)
  LDKT(ktB, 1);
  SYNC_NODRAIN();

// one period; CUR = chunk parity of g
#define BODY(G, KTF, VN, KTC, VC, CUR)                                         \
  {                                                                            \
    int g = (G);                                                               \
    if (g < 62) LDKT(KTF, g + 2);        /* loads FIRST */                     \
    if (g < 63) LDV(VN, g + 1);                                                \
    SB();                                                                      \
    ATTST(CUR, g);                       /* stores after loads */              \
    SB();                                                                      \
    if (g < 63) QKSM(KTC, (CUR) ^ 1);    /* reg MFMA + LDS write */            \
    PV(VC, CUR);                                                               \
    SYNC_NODRAIN();                                                            \
  }

  for (int g2 = 0; g2 < 64; g2 += 2) {
    BODY(g2,     ktA, vB, ktB, vA, 0);   // even: fetch kt(g+2)->A, v(g+1)->B; QK from B; PV from A
    BODY(g2 + 1, ktB, vA, ktA, vB, 1);   // odd: mirrored
  }
#undef LDKT
#undef LDV
#undef QKSM
#undef ATTST
#undef PV
#undef SB
#undef SYNC_NODRAIN
#undef BODY

  // ---- epilogue: out = gamma*acc + x ----
  float gm = gamma[0];
  const float* xb = x + (size_t)b * CC * NN;
  float* ob = out + (size_t)b * CC * NN;
#pragma unroll
  for (int rg2 = 0; rg2 < 4; rg2++)
#pragma unroll
    for (int i = 0; i < 4; i++) {
      int row = c0w + rg2 * 16 + lk * 4 + i;
#pragma unroll
      for (int cg = 0; cg < 4; cg++) {
        int col = m0 + cg * 16 + lr;
        size_t off = (size_t)row * NN + col;
        float xv = __builtin_nontemporal_load(&xb[off]);
        __builtin_nontemporal_store(gm * acc[rg2][cg][i] + xv, &ob[off]);
      }
    }
}

extern "C" void kernel_launch(void* const* d_in, const int* in_sizes, int n_in,
                              void* d_out, int out_size, void* d_ws, size_t ws_size,
                              hipStream_t stream) {
  const float* x  = (const float*)d_in[0];
  const float* y  = (const float*)d_in[1];
  const float* wq = (const float*)d_in[2];
  const float* bq = (const float*)d_in[3];
  const float* wk = (const float*)d_in[4];
  const float* bk = (const float*)d_in[5];
  const float* wv = (const float*)d_in[6];
  const float* bv = (const float*)d_in[7];
  const float* gamma = (const float*)d_in[8];

  float* out = (float*)d_out;
  float* att = out + (size_t)BB * CC * NN;   // attention region of d_out

  // workspace layout (bytes)
  char* ws = (char*)d_ws;
  unsigned short* yT  = (unsigned short*)(ws);                 // 16 MiB  [B][N][C] bf16
  unsigned short* xT  = (unsigned short*)(ws + 16777216);      // 16 MiB
  unsigned short* q   = (unsigned short*)(ws + 33554432);      // 2 MiB   [B*N][64]
  unsigned short* kt  = (unsigned short*)(ws + 35651584);      // 2 MiB   [B*N][64]
  unsigned short* v   = (unsigned short*)(ws + 37748736);      // 16 MiB  [B][C][N]
  unsigned short* wqb = (unsigned short*)(ws + 54525952);      // 64 KiB
  unsigned short* wkb = (unsigned short*)(ws + 54591488);      // 64 KiB
  unsigned short* wvb = (unsigned short*)(ws + 54657024);      // 512 KiB
  float*          inv = (float*)(ws + 55181312);               // 64 KiB  [B*N]
  if (ws_size < 55246848u) return;  // insufficient scratch -> fail loudly

  k_cvt_w<<<1280, 256, 0, stream>>>(wq, wk, wv, wqb, wkb, wvb);
  k_transpose<<<dim3(64, 8, 4), 256, 0, stream>>>(y, yT);
  k_transpose<<<dim3(64, 8, 4), 256, 0, stream>>>(x, xT);
  k_proj64<<<256, 256, 0, stream>>>(yT, wqb, bq, q, 1.44269504088896f);  // q pre-scaled by log2(e)
  k_proj64<<<256, 256, 0, stream>>>(yT, wkb, bk, kt, 1.0f);
  k_projv<<<dim3(16, 8, 4), 256, 0, stream>>>(wvb, xT, bv, v);
  k_sminv<<<dim3(128, 4), 512, 0, stream>>>(q, kt, inv);
  k_fused<<<256, 512, 0, stream>>>(q, kt, v, inv, x, gamma, out, att);
}

// Round 14
// 343.944 us; speedup vs baseline: 1.1947x; 1.0048x over previous
//
#include <hip/hip_runtime.h>

// SelfAttn (SAGAN block): B=4, C=512, N=4096, C8=64
// out = gamma * (V @ softmax(Q K^T)^T) + x ; also outputs attention [B,N,N].
// R14: barrier-free fused kernel. Swapped QK^T (A=K,B=Q) puts P row-local;
// att stored directly from acc; PV B-frag built in-register via
// cvt_pk_bf16 + ds_bpermute (wave-local). Zero LDS tiles, one barrier total.

#define BB 4
#define CC 512
#define NN 4096
#define C8V 64

typedef __bf16 bf16x8 __attribute__((ext_vector_type(8)));
typedef float f32x4 __attribute__((ext_vector_type(4)));
typedef float f32x4v __attribute__((ext_vector_type(4)));
typedef unsigned short u16x8 __attribute__((ext_vector_type(8)));

#if __has_builtin(__builtin_amdgcn_exp2f)
#define EXP2(x) __builtin_amdgcn_exp2f(x)
#else
#define EXP2(x) exp2f(x)
#endif

#define MFMA16(a, b, c) __builtin_amdgcn_mfma_f32_16x16x32_bf16((a), (b), (c), 0, 0, 0)
#define CVTPK(d, a, b) asm("v_cvt_pk_bf16_f32 %0, %1, %2" : "=v"(d) : "v"(a), "v"(b))
#define BP(idx, src) __builtin_amdgcn_ds_bpermute((idx), (int)(src))

__device__ __forceinline__ unsigned short f2b(float f) {
  union { float f; unsigned u; } x; x.f = f;
  unsigned u = x.u;
  u += 0x7fffu + ((u >> 16) & 1u);   // RNE round to bf16
  return (unsigned short)(u >> 16);
}

__device__ __forceinline__ bf16x8 ldb8(const unsigned short* p) {
  return *reinterpret_cast<const bf16x8*>(p);
}

// ---------------- weights fp32 -> bf16 ----------------
__global__ __launch_bounds__(256) void k_cvt_w(
    const float* __restrict__ wq, const float* __restrict__ wk, const float* __restrict__ wv,
    unsigned short* __restrict__ wqb, unsigned short* __restrict__ wkb, unsigned short* __restrict__ wvb) {
  int i = blockIdx.x * 256 + threadIdx.x;
  if (i < 32768)        wqb[i] = f2b(wq[i]);
  else if (i < 65536)   wkb[i - 32768] = f2b(wk[i - 32768]);
  else if (i < 327680)  wvb[i - 65536] = f2b(wv[i - 65536]);
}

// ---------------- transpose [C][N] f32 -> [N][C] bf16 (per batch) ----------------
__global__ __launch_bounds__(256) void k_transpose(const float* __restrict__ src,
                                                   unsigned short* __restrict__ dst) {
  __shared__ float tile[64][65];
  int b = blockIdx.z, c0 = blockIdx.y * 64, n0 = blockIdx.x * 64;
  const float* s = src + (size_t)b * CC * NN;
  unsigned short* d = dst + (size_t)b * NN * CC;
  int t = threadIdx.x;
#pragma unroll
  for (int j = 0; j < 4; j++) {
    int idx = t + j * 256, row = idx >> 4, col4 = (idx & 15) * 4;
    f32x4v v4 = *reinterpret_cast<const f32x4v*>(&s[(size_t)(c0 + row) * NN + n0 + col4]);
    tile[row][col4 + 0] = v4.x; tile[row][col4 + 1] = v4.y;
    tile[row][col4 + 2] = v4.z; tile[row][col4 + 3] = v4.w;
  }
  __syncthreads();
#pragma unroll
  for (int j = 0; j < 4; j++) {
    int idx = t + j * 256, nrow = idx >> 4, c4 = (idx & 15) * 4;
    ushort4 o;
    o.x = f2b(tile[c4 + 0][nrow]); o.y = f2b(tile[c4 + 1][nrow]);
    o.z = f2b(tile[c4 + 2][nrow]); o.w = f2b(tile[c4 + 3][nrow]);
    *reinterpret_cast<ushort4*>(&d[(size_t)(n0 + nrow) * CC + c0 + c4]) = o;
  }
}

// ---------------- Q/K projection ----------------
__global__ __launch_bounds__(256) void k_proj64(const unsigned short* __restrict__ aT,
                                                const unsigned short* __restrict__ wb,
                                                const float* __restrict__ bias,
                                                unsigned short* __restrict__ out, float scale) {
  int wave = threadIdx.x >> 6, l = threadIdx.x & 63;
  int r0 = blockIdx.x * 64 + wave * 16;
  int lr = l & 15, lk = l >> 4;
  const unsigned short* arow = aT + (size_t)(r0 + lr) * CC + lk * 8;
  f32x4 acc[4] = {};
  for (int ks = 0; ks < 16; ks++) {
    bf16x8 a = ldb8(arow + ks * 32);
#pragma unroll
    for (int cg = 0; cg < 4; cg++) {
      bf16x8 bfr = ldb8(wb + (size_t)(cg * 16 + lr) * CC + ks * 32 + lk * 8);
      acc[cg] = MFMA16(a, bfr, acc[cg]);
    }
  }
#pragma unroll
  for (int cg = 0; cg < 4; cg++) {
    int o = cg * 16 + lr;
    float bv = bias[o];
#pragma unroll
    for (int i = 0; i < 4; i++) {
      int row = r0 + lk * 4 + i;
      out[(size_t)row * C8V + o] = f2b((acc[cg][i] + bv) * scale);
    }
  }
}

// ---------------- V projection ----------------
__global__ __launch_bounds__(256) void k_projv(const unsigned short* __restrict__ wvb,
                                               const unsigned short* __restrict__ xT,
                                               const float* __restrict__ bv,
                                               unsigned short* __restrict__ v) {
  int b = blockIdx.z, c0 = blockIdx.y * 64;
  int wave = threadIdx.x >> 6, l = threadIdx.x & 63;
  int n0 = blockIdx.x * 256 + wave * 64;
  int lr = l & 15, lk = l >> 4;
  const unsigned short* xb = xT + (size_t)b * NN * CC;
  f32x4 acc[4][4] = {};
  for (int ks = 0; ks < 16; ks++) {
    bf16x8 a[4], bfr[4];
#pragma unroll
    for (int rg = 0; rg < 4; rg++)
      a[rg] = ldb8(wvb + (size_t)(c0 + rg * 16 + lr) * CC + ks * 32 + lk * 8);
#pragma unroll
    for (int cg = 0; cg < 4; cg++)
      bfr[cg] = ldb8(xb + (size_t)(n0 + cg * 16 + lr) * CC + ks * 32 + lk * 8);
#pragma unroll
    for (int rg = 0; rg < 4; rg++)
#pragma unroll
      for (int cg = 0; cg < 4; cg++)
        acc[rg][cg] = MFMA16(a[rg], bfr[cg], acc[rg][cg]);
  }
  unsigned short* vb = v + (size_t)b * CC * NN;
#pragma unroll
  for (int rg = 0; rg < 4; rg++)
#pragma unroll
    for (int i = 0; i < 4; i++) {
      int row = c0 + rg * 16 + lk * 4 + i;
      float bias = bv[row];
#pragma unroll
      for (int cg = 0; cg < 4; cg++) {
        int col = n0 + cg * 16 + lr;
        vb[(size_t)row * NN + col] = f2b(acc[rg][cg][i] + bias);
      }
    }
}

// ---------------- fused: softmax-sum + att write + PV + epilogue ----------------
// Grid 256 (1 block/CU), XCD-pinned. Block = 64 m-rows x full C; 8 waves,
// wave w owns c-rows [w*64, w*64+64) and computes QK^T for ALL 64 m itself
// (8x duplicated -- buys ZERO inter-wave coupling: no LDS tiles, no barriers
// in the main loops; waves drift freely and hide each other's latency).
// Swapped QK^T: mfma(A=kt,B=q) -> lane l holds P[m=l&15][n=4*(l>>4)+i].
// Pass 1 (rowsums): slices strided by wave, combined via ONE barrier.
// Pass 2 per 32-n slice: QK^T -> p=exp2(z)*inv -> att float4 NT store
// (wave w stores slices s%8==w, straight from acc) -> cvt_pk_bf16 +
// ds_bpermute exchange (wave-local transpose to PV B-frag) -> 16 PV MFMA.
__global__ __launch_bounds__(512, 2) void k_fused(const unsigned short* __restrict__ q,
                                                  const unsigned short* __restrict__ kt,
                                                  const unsigned short* __restrict__ v,
                                                  const float* __restrict__ x,
                                                  const float* __restrict__ gamma,
                                                  float* __restrict__ out,
                                                  float* __restrict__ att) {
  __shared__ float psum[8][64];

  int bid = blockIdx.x;
  int b = (bid & 7) >> 1;                       // XCD id = bid % 8
  int m0 = ((bid >> 3) * 2 + (bid & 1)) * 64;   // 64 m-tiles per batch
  int t = threadIdx.x, w = t >> 6, l = t & 63, lr = l & 15, lk = l >> 4;
  int c0w = w * 64;                             // this wave's 64 c-rows

  const unsigned short* ktb = kt + (size_t)b * NN * C8V;
  const unsigned short* vb = v + (size_t)b * CC * NN;
  float* ab = att + (size_t)b * NN * NN;

  // bpermute exchange constants (byte addresses of source lanes)
  int ilo = 4 * (lr + ((lk & 1) << 5));
  int ihi = ilo + 64;
  bool jlt2 = (lk < 2);

  // q B-fragments: col = m = lr, k = ch; 4 m-blocks x 2 k-halves
  bf16x8 qf[4][2];
#pragma unroll
  for (int g = 0; g < 4; g++) {
    const unsigned short* qp = q + (size_t)(b * NN + m0 + g * 16 + lr) * C8V + lk * 8;
    qf[g][0] = ldb8(qp);
    qf[g][1] = ldb8(qp + 32);
  }

#define LDKT(KT, S)                                                            \
  _Pragma("unroll")                                                            \
  for (int nb = 0; nb < 2; nb++)                                               \
    _Pragma("unroll")                                                          \
    for (int kh = 0; kh < 2; kh++)                                             \
      KT[nb][kh] = ldb8(ktb + (size_t)((S) * 32 + nb * 16 + lr) * C8V + kh * 32 + lk * 8);

#define LDVV(VV, S)                                                            \
  _Pragma("unroll")                                                            \
  for (int cb = 0; cb < 4; cb++)                                               \
    VV[cb] = ldb8(vb + (size_t)(c0w + cb * 16 + lr) * NN + (S) * 32 + lk * 8);

  // ---- pass 1: row sums (each wave 16 of 128 slices; one LDS combine) ----
  float rs[4] = {0.f, 0.f, 0.f, 0.f};
  for (int s = w; s < 128; s += 8) {
    bf16x8 k1[2][2];
    LDKT(k1, s);
#pragma unroll
    for (int g = 0; g < 4; g++) {
      f32x4 zA = {}, zB = {};
      zA = MFMA16(k1[0][0], qf[g][0], zA);
      zA = MFMA16(k1[0][1], qf[g][1], zA);
      zB = MFMA16(k1[1][0], qf[g][0], zB);
      zB = MFMA16(k1[1][1], qf[g][1], zB);
#pragma unroll
      for (int i = 0; i < 4; i++) rs[g] += EXP2(zA[i]) + EXP2(zB[i]);
    }
  }
#pragma unroll
  for (int g = 0; g < 4; g++) {
    rs[g] += __shfl_xor(rs[g], 16);
    rs[g] += __shfl_xor(rs[g], 32);
  }
  if (l < 16) {
#pragma unroll
    for (int g = 0; g < 4; g++) psum[w][g * 16 + l] = rs[g];
  }
  __syncthreads();                // the ONLY barrier in this kernel
  float inv_[4];
#pragma unroll
  for (int g = 0; g < 4; g++) {
    float s = 0.f;
#pragma unroll
    for (int ww = 0; ww < 8; ww++) s += psum[ww][g * 16 + lr];
    inv_[g] = 1.0f / s;
  }

  // ---- pass 2: QK^T -> att store + in-register exchange -> PV ----
#define COMPUTE(S, KT, VV)                                                     \
  {                                                                            \
    bool dost = (((S) & 7) == w);                                              \
    bf16x8 bfr[4];                                                             \
    _Pragma("unroll")                                                          \
    for (int g = 0; g < 4; g++) {                                              \
      f32x4 zA = {}, zB = {};                                                  \
      zA = MFMA16(KT[0][0], qf[g][0], zA);                                     \
      zA = MFMA16(KT[0][1], qf[g][1], zA);                                     \
      zB = MFMA16(KT[1][0], qf[g][0], zB);                                     \
      zB = MFMA16(KT[1][1], qf[g][1], zB);                                     \
      f32x4v pA, pB;                                                           \
      _Pragma("unroll")                                                        \
      for (int i = 0; i < 4; i++) {                                            \
        pA[i] = EXP2(zA[i]) * inv_[g];                                         \
        pB[i] = EXP2(zB[i]) * inv_[g];                                         \
      }                                                                        \
      if (dost) {                                                              \
        float* dr = &ab[(size_t)(m0 + g * 16 + lr) * NN + (S) * 32 + lk * 4];  \
        __builtin_nontemporal_store(pA, reinterpret_cast<f32x4v*>(dr));        \
        __builtin_nontemporal_store(pB, reinterpret_cast<f32x4v*>(dr + 16));   \
      }                                                                        \
      unsigned a0, b0, a1, b1;                                                 \
      CVTPK(a0, pA[0], pA[1]); CVTPK(b0, pA[2], pA[3]);                        \
      CVTPK(a1, pB[0], pB[1]); CVTPK(b1, pB[2], pB[3]);                        \
      int t0 = BP(ilo, a0), u0 = BP(ilo, a1);                                  \
      int t1 = BP(ilo, b0), u1 = BP(ilo, b1);                                  \
      int t2 = BP(ihi, a0), u2 = BP(ihi, a1);                                  \
      int t3 = BP(ihi, b0), u3 = BP(ihi, b1);                                  \
      union { int d[4]; bf16x8 v8; } bu;                                       \
      bu.d[0] = jlt2 ? t0 : u0;                                                \
      bu.d[1] = jlt2 ? t1 : u1;                                                \
      bu.d[2] = jlt2 ? t2 : u2;                                                \
      bu.d[3] = jlt2 ? t3 : u3;                                                \
      bfr[g] = bu.v8;                                                          \
    }                                                                          \
    _Pragma("unroll")                                                          \
    for (int cb = 0; cb < 4; cb++)                                             \
      _Pragma("unroll")                                                        \
      for (int g = 0; g < 4; g++)                                              \
        acc[cb][g] = MFMA16(VV[cb], bfr[g], acc[cb][g]);                       \
  }

  f32x4 acc[4][4] = {};
  bf16x8 ktA[2][2], ktB[2][2], vA[4], vB[4];

  LDKT(ktA, 0);
  LDVV(vA, 0);
  for (int s = 0; s < 128; s += 2) {
    LDKT(ktB, s + 1);             // loads for s+1 issue BEFORE stores of s
    LDVV(vB, s + 1);
    COMPUTE(s, ktA, vA);
    if (s + 2 < 128) {
      LDKT(ktA, s + 2);
      LDVV(vA, s + 2);
    }
    COMPUTE(s + 1, ktB, vB);
  }
#undef LDKT
#undef LDVV
#undef COMPUTE

  // ---- epilogue: out = gamma*acc + x ----
  float gm = gamma[0];
  const float* xb = x + (size_t)b * CC * NN;
  float* ob = out + (size_t)b * CC * NN;
#pragma unroll
  for (int cb = 0; cb < 4; cb++)
#pragma unroll
    for (int i = 0; i < 4; i++) {
      int row = c0w + cb * 16 + lk * 4 + i;
#pragma unroll
      for (int g = 0; g < 4; g++) {
        int col = m0 + g * 16 + lr;
        size_t off = (size_t)row * NN + col;
        float xv = __builtin_nontemporal_load(&xb[off]);
        __builtin_nontemporal_store(gm * acc[cb][g][i] + xv, &ob[off]);
      }
    }
}

extern "C" void kernel_launch(void* const* d_in, const int* in_sizes, int n_in,
                              void* d_out, int out_size, void* d_ws, size_t ws_size,
                              hipStream_t stream) {
  const float* x  = (const float*)d_in[0];
  const float* y  = (const float*)d_in[1];
  const float* wq = (const float*)d_in[2];
  const float* bq = (const float*)d_in[3];
  const float* wk = (const float*)d_in[4];
  const float* bk = (const float*)d_in[5];
  const float* wv = (const float*)d_in[6];
  const float* bv = (const float*)d_in[7];
  const float* gamma = (const float*)d_in[8];

  float* out = (float*)d_out;
  float* att = out + (size_t)BB * CC * NN;   // attention region of d_out

  // workspace layout (bytes)
  char* ws = (char*)d_ws;
  unsigned short* yT  = (unsigned short*)(ws);                 // 16 MiB  [B][N][C] bf16
  unsigned short* xT  = (unsigned short*)(ws + 16777216);      // 16 MiB
  unsigned short* q   = (unsigned short*)(ws + 33554432);      // 2 MiB   [B*N][64]
  unsigned short* kt  = (unsigned short*)(ws + 35651584);      // 2 MiB   [B*N][64]
  unsigned short* v   = (unsigned short*)(ws + 37748736);      // 16 MiB  [B][C][N]
  unsigned short* wqb = (unsigned short*)(ws + 54525952);      // 64 KiB
  unsigned short* wkb = (unsigned short*)(ws + 54591488);      // 64 KiB
  unsigned short* wvb = (unsigned short*)(ws + 54657024);      // 512 KiB
  if (ws_size < 55181312u) return;  // insufficient scratch -> fail loudly

  k_cvt_w<<<1280, 256, 0, stream>>>(wq, wk, wv, wqb, wkb, wvb);
  k_transpose<<<dim3(64, 8, 4), 256, 0, stream>>>(y, yT);
  k_transpose<<<dim3(64, 8, 4), 256, 0, stream>>>(x, xT);
  k_proj64<<<256, 256, 0, stream>>>(yT, wqb, bq, q, 1.44269504088896f);  // q pre-scaled by log2(e)
  k_proj64<<<256, 256, 0, stream>>>(yT, wkb, bk, kt, 1.0f);
  k_projv<<<dim3(16, 8, 4), 256, 0, stream>>>(wvb, xT, bv, v);
  k_fused<<<256, 512, 0, stream>>>(q, kt, v, x, gamma, out, att);
}